// Round 1
// baseline (8176.736 us; speedup 1.0000x reference)
//
#include <hip/hip_runtime.h>
#include <cstdint>

typedef unsigned long long u64;

#define B_   64
#define L_   1024
#define D_   256
#define H_   256
#define G4_  1024
#define NROW (B_*L_)   // 65536

// ===================== Kernel 1: xproj = x @ W_ih^T + b_ih =====================
// x: [65536,256] row-major, W_ih: [1024,256] row-major, xproj: [65536,1024]
#define TM 128
#define TN 128
#define KC 16

__global__ __launch_bounds__(256)
void xproj_gemm(const float* __restrict__ x, const float* __restrict__ Wih,
                const float* __restrict__ bih, float* __restrict__ xp)
{
  __shared__ float As[2][KC][TM];
  __shared__ float Bs[2][KC][TN];
  const int tid = threadIdx.x;
  const int bn = blockIdx.x & 7;        // 8 col tiles
  const int bm = blockIdx.x >> 3;       // 512 row tiles
  const long R0 = (long)bm * TM;
  const int  C0 = bn * TN;
  const int tx = tid & 15, ty = tid >> 4;

  float acc[8][8];
#pragma unroll
  for (int i = 0; i < 8; i++)
#pragma unroll
    for (int j = 0; j < 8; j++) acc[i][j] = 0.f;

  float4 areg[2], breg[2];

  // stage chunk 0
#pragma unroll
  for (int rep = 0; rep < 2; rep++) {
    int f4 = rep * 256 + tid;
    int rw = f4 & 127, kq = f4 >> 7;
    areg[rep] = *(const float4*)(x   + (R0 + rw) * D_ + kq * 4);
    breg[rep] = *(const float4*)(Wih + (long)(C0 + rw) * D_ + kq * 4);
  }
#pragma unroll
  for (int rep = 0; rep < 2; rep++) {
    int f4 = rep * 256 + tid;
    int rw = f4 & 127, kq = f4 >> 7;
#pragma unroll
    for (int i2 = 0; i2 < 4; i2++) {
      As[0][kq * 4 + i2][rw] = ((const float*)&areg[rep])[i2];
      Bs[0][kq * 4 + i2][rw] = ((const float*)&breg[rep])[i2];
    }
  }
  __syncthreads();

  int buf = 0;
  const int NKB = D_ / KC; // 16
  for (int kb = 0; kb < NKB; kb++) {
    if (kb + 1 < NKB) {
#pragma unroll
      for (int rep = 0; rep < 2; rep++) {
        int f4 = rep * 256 + tid;
        int rw = f4 & 127, kq = f4 >> 7;
        areg[rep] = *(const float4*)(x   + (R0 + rw) * D_ + (kb + 1) * KC + kq * 4);
        breg[rep] = *(const float4*)(Wih + (long)(C0 + rw) * D_ + (kb + 1) * KC + kq * 4);
      }
    }
#pragma unroll
    for (int kk = 0; kk < KC; kk++) {
      float4 a0 = *(const float4*)&As[buf][kk][tx * 4];
      float4 a1 = *(const float4*)&As[buf][kk][tx * 4 + 64];
      float4 b0 = *(const float4*)&Bs[buf][kk][ty * 4];
      float4 b1 = *(const float4*)&Bs[buf][kk][ty * 4 + 64];
      float av[8] = {a0.x,a0.y,a0.z,a0.w,a1.x,a1.y,a1.z,a1.w};
      float bv[8] = {b0.x,b0.y,b0.z,b0.w,b1.x,b1.y,b1.z,b1.w};
#pragma unroll
      for (int i = 0; i < 8; i++)
#pragma unroll
        for (int j = 0; j < 8; j++) acc[i][j] += av[i] * bv[j];
    }
    if (kb + 1 < NKB) {
#pragma unroll
      for (int rep = 0; rep < 2; rep++) {
        int f4 = rep * 256 + tid;
        int rw = f4 & 127, kq = f4 >> 7;
#pragma unroll
        for (int i2 = 0; i2 < 4; i2++) {
          As[buf ^ 1][kq * 4 + i2][rw] = ((const float*)&areg[rep])[i2];
          Bs[buf ^ 1][kq * 4 + i2][rw] = ((const float*)&breg[rep])[i2];
        }
      }
    }
    __syncthreads();
    buf ^= 1;
  }

  float4 bb0 = *(const float4*)(bih + C0 + ty * 4);
  float4 bb1 = *(const float4*)(bih + C0 + ty * 4 + 64);
#pragma unroll
  for (int i = 0; i < 8; i++) {
    long m = R0 + tx * 4 + ((i < 4) ? i : (60 + i));
    float4 v0, v1;
    v0.x = acc[i][0] + bb0.x; v0.y = acc[i][1] + bb0.y;
    v0.z = acc[i][2] + bb0.z; v0.w = acc[i][3] + bb0.w;
    v1.x = acc[i][4] + bb1.x; v1.y = acc[i][5] + bb1.y;
    v1.z = acc[i][6] + bb1.z; v1.w = acc[i][7] + bb1.w;
    *(float4*)(xp + m * G4_ + C0 + ty * 4)      = v0;
    *(float4*)(xp + m * G4_ + C0 + ty * 4 + 64) = v1;
  }
}

// ===================== Kernel 2: persistent bidirectional recurrence =====================
// 16 chains (4 batch rows each) x 16 blocks (16 h-cols / 64 gate rows each).
// W_hh slice lives in VGPRs (64 floats/thread). h exchanged via tagged 8B words
// (tag = step) through device-scope relaxed atomics; double-buffered by parity.
#define RPB 4      // batch rows per chain
#define CPB 16     // h cols per block

__global__ __launch_bounds__(256)
void lstm_recur(const float* __restrict__ xp, const float* __restrict__ mask,
                const float* __restrict__ Whh, const float* __restrict__ bhh,
                float* __restrict__ out, u64* __restrict__ hstate)
{
  __shared__ float hbuf[RPB][H_];      // h_{t-1} for this chain's 4 rows
  __shared__ float part[4][RPB][64];   // [kc][r][j] partial dots
  __shared__ float gbuf[RPB][64];      // summed gates
  __shared__ float mbuf[2][RPB];       // mask prefetch ring

  const int tid   = threadIdx.x;
  const int bid   = blockIdx.x;
  const int chain = bid >> 4;          // batch group 0..15
  const int gg    = bid & 15;          // gate group 0..15
  const int kc    = tid >> 6;          // wave = k-chunk, also r for gate-sum
  const int j     = tid & 63;          // lane = gate row in slice
  const int q     = j >> 4;            // gate type i/f/g/o
  const int cc    = j & 15;            // col within group

  // W_hh slice row for this thread's j, 64 k-values in registers
  const int wrow = q * H_ + gg * CPB + cc;
  float4 wreg[16];
  {
    const float4* wr = (const float4*)(Whh + (long)wrow * H_ + kc * 64);
#pragma unroll
    for (int u = 0; u < 16; u++) wreg[u] = wr[u];
  }
  const float bhh_r = bhh[wrow];

  // elementwise / spin mapping for tid<64
  const int er = tid >> 4, ec = tid & 15;
  const int sk0 = ec * 16;
  const long erow = (long)chain * RPB + er;

  const long xp_base = (long)(chain * RPB + kc) * L_;
  const int  gcol = q * H_ + gg * CPB + cc;

  float hreg = 0.f, creg = 0.f;   // own h/c state (tid<64)
  int dead = 0;

  // prologue prefetch for s=1 (t=0)
  float xp_cur = xp[xp_base * G4_ + gcol];
  if (tid < RPB) mbuf[1][tid] = mask[(chain * RPB + tid) * L_];
  __syncthreads();

  for (int s = 1; s <= 2048; s++) {
    const int t   = (s <= 1024) ? (s - 1) : (2048 - s);
    const int sp  = (s < 2048) ? (s + 1) : 2048;
    const int tp  = (sp <= 1024) ? (sp - 1) : (2048 - sp);
    const int dir = (s <= 1024) ? 0 : 1;

    // issue next-step prefetches immediately (latency hidden by spin+compute)
    float xp_nxt = xp[(xp_base + tp) * G4_ + gcol];
    float mv = 0.f;
    if (tid < RPB) mv = mask[(chain * RPB + tid) * L_ + tp];

    // acquire h_{s-1} (tagged words) into LDS
    if (s > 1) {
      if (tid < 64) {
        const u64* hp = hstate + (size_t)((s - 1) & 1) * B_ * H_
                        + ((size_t)chain * RPB + er) * H_ + sk0;
        u64 uu[16];
        const u64 want = (u64)(s - 1);
        int iter = 0, ok = 0;
        const int cap = dead ? 1 : 200000;
        do {
          ok = 1;
#pragma unroll
          for (int i2 = 0; i2 < 16; i2++)
            uu[i2] = __hip_atomic_load(hp + i2, __ATOMIC_RELAXED, __HIP_MEMORY_SCOPE_AGENT);
#pragma unroll
          for (int i2 = 0; i2 < 16; i2++) ok &= ((int)(uu[i2] >> 32) == (int)want);
        } while (!ok && ++iter < cap);
        if (!ok) dead = 1;
#pragma unroll
        for (int i2 = 0; i2 < 16; i2 += 4) {
          float4 f4;
          f4.x = __uint_as_float((unsigned)uu[i2 + 0]);
          f4.y = __uint_as_float((unsigned)uu[i2 + 1]);
          f4.z = __uint_as_float((unsigned)uu[i2 + 2]);
          f4.w = __uint_as_float((unsigned)uu[i2 + 3]);
          *(float4*)&hbuf[er][sk0 + i2] = f4;
        }
      }
    } else {
      if (tid < 64) {
#pragma unroll
        for (int i2 = 0; i2 < 16; i2 += 4) {
          float4 z = {0.f, 0.f, 0.f, 0.f};
          *(float4*)&hbuf[er][sk0 + i2] = z;
        }
      }
    }
    __syncthreads();   // bar1: hbuf ready

    // k-loop: partial dot over this wave's 64 k values, 4 batch rows
    float a0 = 0.f, a1 = 0.f, a2 = 0.f, a3 = 0.f;
    {
      const float4* hb = ((const float4*)hbuf) + kc * 16;
#pragma unroll
      for (int u = 0; u < 16; u++) {
        float4 w4 = wreg[u];
        float4 h0 = hb[u];
        float4 h1 = hb[64 + u];
        float4 h2 = hb[128 + u];
        float4 h3 = hb[192 + u];
        a0 += w4.x*h0.x + w4.y*h0.y + w4.z*h0.z + w4.w*h0.w;
        a1 += w4.x*h1.x + w4.y*h1.y + w4.z*h1.z + w4.w*h1.w;
        a2 += w4.x*h2.x + w4.y*h2.y + w4.z*h2.z + w4.w*h2.w;
        a3 += w4.x*h3.x + w4.y*h3.y + w4.z*h3.z + w4.w*h3.w;
      }
    }
    part[kc][0][j] = a0; part[kc][1][j] = a1;
    part[kc][2][j] = a2; part[kc][3][j] = a3;
    __syncthreads();   // bar2: partials ready

    // gate sum: thread (kc as r, j)
    gbuf[kc][j] = part[0][kc][j] + part[1][kc][j] + part[2][kc][j] + part[3][kc][j]
                + xp_cur + bhh_r;
    __syncthreads();   // bar3: gates ready

    // elementwise LSTM cell: tid<64, thread owns (er, ec)
    if (tid < 64) {
      float iv = gbuf[er][ec];
      float fv = gbuf[er][16 + ec];
      float gv = gbuf[er][32 + ec];
      float ov = gbuf[er][48 + ec];
      float si = 1.f / (1.f + expf(-iv));
      float sf = 1.f / (1.f + expf(-fv));
      float so = 1.f / (1.f + expf(-ov));
      float c1 = sf * creg + si * tanhf(gv);
      float h1 = so * tanhf(c1);
      float m  = mbuf[s & 1][er];
      float hn = m * h1 + (1.f - m) * hreg;
      float cn = m * c1 + 1.f - m * creg;   // replicates reference parenthesization
      hreg = hn; creg = cn;

      out[erow * L_ * 512 + (long)t * 512 + dir * H_ + gg * CPB + ec] = hn;

      u64 pack = ((u64)(unsigned)s << 32) | (u64)__float_as_uint(hn);
      __hip_atomic_store(hstate + (size_t)(s & 1) * B_ * H_ + erow * H_ + gg * CPB + ec,
                         pack, __ATOMIC_RELAXED, __HIP_MEMORY_SCOPE_AGENT);

      if (s == 1024 || s == 2048) {
        const long off_hn = (long)B_ * L_ * 512;
        out[off_hn + erow * 512 + dir * H_ + gg * CPB + ec] = hn;           // h_n
        out[off_hn + 32768 + erow * 512 + dir * H_ + gg * CPB + ec] = cn;  // c_n
      }
    }

    xp_cur = xp_nxt;
    if (tid < RPB) mbuf[(s + 1) & 1][tid] = mv;
  }
}

// ===================== launcher =====================
extern "C" void kernel_launch(void* const* d_in, const int* in_sizes, int n_in,
                              void* d_out, int out_size, void* d_ws, size_t ws_size,
                              hipStream_t stream)
{
  const float* x    = (const float*)d_in[0];
  const float* mask = (const float*)d_in[1];
  const float* Wih  = (const float*)d_in[2];
  const float* Whh  = (const float*)d_in[3];
  const float* bih  = (const float*)d_in[4];
  const float* bhh  = (const float*)d_in[5];
  float* out = (float*)d_out;

  float* xp     = (float*)d_ws;                                  // 256 MB
  u64*   hstate = (u64*)((char*)d_ws + (size_t)NROW * G4_ * 4);  // 256 KB

  const size_t need = (size_t)NROW * G4_ * 4 + (size_t)2 * B_ * H_ * 8;
  if (ws_size < need) return;  // workspace too small: bail (wrong answer, no crash)

  xproj_gemm<<<dim3(512 * 8), dim3(256), 0, stream>>>(x, Wih, bih, xp);

  void* args[] = { (void*)&xp, (void*)&mask, (void*)&Whh, (void*)&bhh,
                   (void*)&out, (void*)&hstate };
  hipLaunchCooperativeKernel((void*)lstm_recur, dim3(256), dim3(256), args, 0, stream);
}